// Round 10
// baseline (194.983 us; speedup 1.0000x reference)
//
#include <hip/hip_runtime.h>
#include <math.h>

typedef unsigned int u32;
typedef unsigned long long u64;
typedef long long i64;
typedef float float4n __attribute__((ext_vector_type(4)));   // native vec for nontemporal builtins
typedef u32   uint4n  __attribute__((ext_vector_type(4)));

#define BINS 256
#define TBITS 0x40000000u    /* bit pattern of 2.0f : compaction threshold          */
#define A_BASE 131072u       /* TBITS >> 13                                         */
#define A_BINS 4096          /* covers |x| in [2, 32)                               */
#define B_BINS 8192          /* low 13 bits                                         */
#define SLOT 1152            /* per-block candidate slot (mean ~745, +15 sigma)     */
#define NBLK 512             /* blocks per channel for full passes                  */

// ---------------- helpers ----------------

// Bit-exact replica of the float32 numpy pipeline:
//   idx = trunc(min(|x|/mv, 1.0f) * 255.0f)   (*8 and /8 are exact pow2 ops)
__device__ __forceinline__ int bin_index_f32(float xv, float mv) {
    float r = __fdiv_rn(fabsf(xv), mv);
    r = fminf(r, 1.0f);
    return (int)__fmul_rn(r, 255.0f);
}

// Parallel rank-select over h[0..256*PER) for `target`; one thread writes
// res[0]=bucket, res[1]=target-cum_excl(bucket). Caller zeroes res, syncs after.
template<int PER>
__device__ void block_select(const u32* __restrict__ h, u32 target,
                             u32* ssum, u32* res) {
    const int t = threadIdx.x;
    u32 loc[PER];
    u32 s = 0;
    const int base = t * PER;
#pragma unroll
    for (int j = 0; j < PER; ++j) { loc[j] = h[base + j]; s += loc[j]; }
    ssum[t] = s;
    __syncthreads();
    for (int off = 1; off < 256; off <<= 1) {
        u32 add = (t >= off) ? ssum[t - off] : 0;
        __syncthreads();
        ssum[t] += add;
        __syncthreads();
    }
    u32 cum = ssum[t] - s;
#pragma unroll
    for (int j = 0; j < PER; ++j) {
        u32 cnt = loc[j];
        if (target >= cum && target < cum + cnt) { res[0] = (u32)(base + j); res[1] = target - cum; }
        cum += cnt;
    }
    __syncthreads();
}

// numpy float32 _lerp between exact order stats v0bits <= v1bits
__device__ __forceinline__ float np_lerp_f32(u32 v0bits, u32 v1bits, double gamma) {
    float v0 = __uint_as_float(v0bits);
    float v1 = __uint_as_float(v1bits);
    float dba = __fsub_rn(v1, v0);
    float q;
    if (gamma >= 0.5) q = __fsub_rn(v1, __fmul_rn(dba, (float)(1.0 - gamma)));
    else              q = __fadd_rn(v0, __fmul_rn(dba, (float)gamma));
    return fmaxf(q, 1e-8f);
}

// Wave-aggregated candidate append: one lcnt atomic per wave per component.
__device__ __forceinline__ void append_cand(u32 b, u32* lbuf, u32* lcnt,
                                            u32* lha, u32* loob) {
    const bool pred = (b >= TBITS);
    u64 m = __ballot(pred);
    if (m) {
        const int lane = threadIdx.x & 63;
        const int leader = __ffsll((unsigned long long)m) - 1;
        u32 base = 0;
        if (lane == leader) base = atomicAdd(lcnt, (u32)__popcll(m));
        base = __shfl(base, leader, 64);
        if (pred) {
            u32 p = base + (u32)__popcll(m & ((1ull << lane) - 1ull));
            if (p < SLOT) lbuf[p] = b;
            u32 bin = (b >> 13) - A_BASE;
            if (bin >= A_BINS) { atomicAdd(loob, 1u); bin = A_BINS - 1; }
            atomicAdd(&lha[bin], 1u);
        }
    }
}

// ---------------- pass 1: streaming threshold-compaction + fused 4096-bin candidate hist ----------------

__global__ __launch_bounds__(256) void k_pass1(const float* __restrict__ x, u32* __restrict__ cand,
                                               u32* __restrict__ gha, u32* __restrict__ oflow,
                                               u32* __restrict__ goob, i64 nper, int do_cand) {
    __shared__ u32 lbuf[SLOT];
    __shared__ u32 lha[A_BINS];
    __shared__ u32 lcnt, loob;
    const int c = blockIdx.y;
    for (int i = threadIdx.x; i < A_BINS; i += 256) lha[i] = 0;
    if (threadIdx.x == 0) { lcnt = 0; loob = 0; }
    __syncthreads();
    const float* xc = x + (i64)c * nper;
    const i64 nv = nper >> 2;
    const float4* xv = (const float4*)xc;
    for (i64 i = (i64)blockIdx.x * 256 + threadIdx.x; i < nv; i += (i64)gridDim.x * 256) {
        float4 v = xv[i];
        append_cand(__float_as_uint(fabsf(v.x)), lbuf, &lcnt, lha, &loob);
        append_cand(__float_as_uint(fabsf(v.y)), lbuf, &lcnt, lha, &loob);
        append_cand(__float_as_uint(fabsf(v.z)), lbuf, &lcnt, lha, &loob);
        append_cand(__float_as_uint(fabsf(v.w)), lbuf, &lcnt, lha, &loob);
    }
    if (blockIdx.x == 0 && threadIdx.x < (int)(nper & 3)) {
        append_cand(__float_as_uint(fabsf(xc[nv * 4 + threadIdx.x])), lbuf, &lcnt, lha, &loob);
    }
    __syncthreads();
    for (int i = threadIdx.x; i < A_BINS; i += 256)
        if (lha[i]) atomicAdd(&gha[c * A_BINS + i], lha[i]);
    if (threadIdx.x == 0) {
        if (loob) atomicExch(&goob[c], 1u);
        if (lcnt > SLOT) { atomicExch(&oflow[c], 1u); lcnt = SLOT; }
    }
    __syncthreads();
    if (do_cand) {
        const u32 cnt = lcnt;
        u32* slot = cand + ((i64)c * gridDim.x + blockIdx.x) * SLOT;
        for (u32 j = threadIdx.x; j < SLOT; j += 256) {
            u32 val = (j < cnt) ? lbuf[j] : 0u;   // pad = 0, below every candidate
            __builtin_nontemporal_store(val, &slot[j]);   // single-use buffer: keep L3 for x
        }
    }
}

// ---------------- stage B hist, with per-block redundant A-pick (deterministic) ----------------

__global__ __launch_bounds__(256) void k_cselB_hist(const u32* __restrict__ cand, const u32* __restrict__ gha,
                                                    const u32* __restrict__ oflow, const u32* __restrict__ goob,
                                                    u32* __restrict__ flag, u32* __restrict__ cselA,
                                                    u32* __restrict__ g3a, u32* __restrict__ g3b,
                                                    i64 ntot, u32 needed) {
    __shared__ u32 la[B_BINS], lb[B_BINS];
    __shared__ u32 ssum[256];
    __shared__ u32 prA[4];
    __shared__ u32 s_total;
    const int c = blockIdx.y;
    const int t = threadIdx.x;
    // A-pick: every block computes it from gha (identical input -> identical result)
    if (t < 4) prA[t] = 0;
    const u32* h = gha + c * A_BINS;
    u32 loc[16];
    u32 s = 0;
    const int base = t * 16;
#pragma unroll
    for (int j = 0; j < 16; ++j) { loc[j] = h[base + j]; s += loc[j]; }
    ssum[t] = s;
    __syncthreads();
    for (int off = 1; off < 256; off <<= 1) {
        u32 add = (t >= off) ? ssum[t - off] : 0;
        __syncthreads();
        ssum[t] += add;
        __syncthreads();
    }
    if (t == 255) s_total = ssum[255];
    __syncthreads();
    const u32 total = s_total;
    const u32 bad = (oflow[c] != 0) || (goob[c] != 0) || (total < needed) || (needed < 2);
    if (bad) {
        if (blockIdx.x == 0 && t == 0) flag[c] = 1u;
        return;
    }
    const u32 t0 = total - needed;
    const u32 t1 = t0 + 1;
    u32 cum = ssum[t] - s;
#pragma unroll
    for (int j = 0; j < 16; ++j) {
        u32 cnt = loc[j];
        if (t0 >= cum && t0 < cum + cnt) { prA[0] = (u32)(base + j); prA[1] = t0 - cum; }
        if (t1 >= cum && t1 < cum + cnt) { prA[2] = (u32)(base + j); prA[3] = t1 - cum; }
        cum += cnt;
    }
    __syncthreads();
    const u32 topA0 = A_BASE + prA[0];
    const u32 topA1 = A_BASE + prA[2];
    if (blockIdx.x == 0 && t == 0) {
        flag[c] = 0u;
        cselA[c * 4 + 0] = prA[0]; cselA[c * 4 + 1] = prA[1];
        cselA[c * 4 + 2] = prA[2]; cselA[c * 4 + 3] = prA[3];
    }
    // B-level histogram of the two selected A-buckets
    for (int i = t; i < B_BINS; i += 256) { la[i] = 0; lb[i] = 0; }
    __syncthreads();
    const uint4n* cd = (const uint4n*)(cand + (i64)c * ntot);
    const i64 nv4 = ntot >> 2;
    for (i64 i = (i64)blockIdx.x * 256 + t; i < nv4; i += (i64)gridDim.x * 256) {
        uint4n v = __builtin_nontemporal_load(&cd[i]);
        u32 b;
        b = v.x;
        if (b >= TBITS) { u32 tb = b >> 13; if (tb == topA0) atomicAdd(&la[b & (B_BINS - 1)], 1u); if (tb == topA1) atomicAdd(&lb[b & (B_BINS - 1)], 1u); }
        b = v.y;
        if (b >= TBITS) { u32 tb = b >> 13; if (tb == topA0) atomicAdd(&la[b & (B_BINS - 1)], 1u); if (tb == topA1) atomicAdd(&lb[b & (B_BINS - 1)], 1u); }
        b = v.z;
        if (b >= TBITS) { u32 tb = b >> 13; if (tb == topA0) atomicAdd(&la[b & (B_BINS - 1)], 1u); if (tb == topA1) atomicAdd(&lb[b & (B_BINS - 1)], 1u); }
        b = v.w;
        if (b >= TBITS) { u32 tb = b >> 13; if (tb == topA0) atomicAdd(&la[b & (B_BINS - 1)], 1u); if (tb == topA1) atomicAdd(&lb[b & (B_BINS - 1)], 1u); }
    }
    __syncthreads();
    for (int i = t; i < B_BINS; i += 256) {
        if (la[i]) atomicAdd(&g3a[c * B_BINS + i], la[i]);
        if (lb[i]) atomicAdd(&g3b[c * B_BINS + i], lb[i]);
    }
}

__global__ void k_flag_force(u32* __restrict__ flag, int C) {
    if (threadIdx.x < C) flag[threadIdx.x] = 1u;
}

// ---------------- mv finalize: B-pick + lerp, OR self-contained exact fallback ----------------

__global__ __launch_bounds__(256) void k_mv_final(const float* __restrict__ x, const u32* __restrict__ flag,
                                                  const u32* __restrict__ cselA,
                                                  const u32* __restrict__ g3a, const u32* __restrict__ g3b,
                                                  float* __restrict__ mv, i64 nper, u32 k0, double gamma) {
    __shared__ u32 h0[2048], h1[2048];
    __shared__ u32 ssum[256];
    __shared__ u32 pr[4];
    __shared__ u32 st[4];
    const int c = blockIdx.x;
    const int t = threadIdx.x;

    if (!flag[c]) {
        if (t < 4) pr[t] = 0;
        __syncthreads();
        block_select<32>(g3a + c * B_BINS, cselA[c * 4 + 1], ssum, &pr[0]);
        block_select<32>(g3b + c * B_BINS, cselA[c * 4 + 3], ssum, &pr[2]);
        if (t == 0) {
            u32 v0bits = ((A_BASE + cselA[c * 4 + 0]) << 13) | pr[0];
            u32 v1bits = ((A_BASE + cselA[c * 4 + 2]) << 13) | pr[2];
            mv[c] = np_lerp_f32(v0bits, v1bits, gamma);
        }
        return;
    }

    // ---- fallback: in-block 3-level exact select over the full channel ----
    const float* xc = x + (i64)c * nper;
    const i64 nv = nper >> 2;
    const int rem = (int)(nper & 3);
    const float4* xv = (const float4*)xc;

    // level 1: bits 31..21 (1024 bins)
    for (int i = t; i < 1024; i += 256) h0[i] = 0;
    __syncthreads();
    for (i64 i = t; i < nv; i += 256) {
        float4 v = xv[i];
        atomicAdd(&h0[__float_as_uint(fabsf(v.x)) >> 21], 1u);
        atomicAdd(&h0[__float_as_uint(fabsf(v.y)) >> 21], 1u);
        atomicAdd(&h0[__float_as_uint(fabsf(v.z)) >> 21], 1u);
        atomicAdd(&h0[__float_as_uint(fabsf(v.w)) >> 21], 1u);
    }
    if (t < rem) atomicAdd(&h0[__float_as_uint(fabsf(xc[nv * 4 + t])) >> 21], 1u);
    __syncthreads();
    if (t < 4) pr[t] = 0;
    __syncthreads();
    block_select<4>(h0, k0, ssum, &pr[0]);
    block_select<4>(h0, k0 + 1, ssum, &pr[2]);
    if (t < 4) st[t] = pr[t];
    __syncthreads();

    // level 2: bits 20..10 (2048 bins, two chains)
    const u32 p0 = st[0], p1 = st[2];
    for (int i = t; i < 2048; i += 256) { h0[i] = 0; h1[i] = 0; }
    __syncthreads();
    for (i64 i = t; i < nv; i += 256) {
        float4 v = xv[i];
        u32 b;
        b = __float_as_uint(fabsf(v.x));
        if ((b >> 21) == p0) atomicAdd(&h0[(b >> 10) & 2047], 1u);
        if ((b >> 21) == p1) atomicAdd(&h1[(b >> 10) & 2047], 1u);
        b = __float_as_uint(fabsf(v.y));
        if ((b >> 21) == p0) atomicAdd(&h0[(b >> 10) & 2047], 1u);
        if ((b >> 21) == p1) atomicAdd(&h1[(b >> 10) & 2047], 1u);
        b = __float_as_uint(fabsf(v.z));
        if ((b >> 21) == p0) atomicAdd(&h0[(b >> 10) & 2047], 1u);
        if ((b >> 21) == p1) atomicAdd(&h1[(b >> 10) & 2047], 1u);
        b = __float_as_uint(fabsf(v.w));
        if ((b >> 21) == p0) atomicAdd(&h0[(b >> 10) & 2047], 1u);
        if ((b >> 21) == p1) atomicAdd(&h1[(b >> 10) & 2047], 1u);
    }
    if (t < rem) {
        u32 b = __float_as_uint(fabsf(xc[nv * 4 + t]));
        if ((b >> 21) == p0) atomicAdd(&h0[(b >> 10) & 2047], 1u);
        if ((b >> 21) == p1) atomicAdd(&h1[(b >> 10) & 2047], 1u);
    }
    __syncthreads();
    if (t < 4) pr[t] = 0;
    __syncthreads();
    block_select<8>(h0, st[1], ssum, &pr[0]);
    block_select<8>(h1, st[3], ssum, &pr[2]);
    if (t == 0) { st[0] = (p0 << 11) | pr[0]; st[1] = pr[1]; st[2] = (p1 << 11) | pr[2]; st[3] = pr[3]; }
    __syncthreads();

    // level 3: bits 9..0 (1024 bins, two chains)
    const u32 q0 = st[0], q1 = st[2];
    for (int i = t; i < 1024; i += 256) { h0[i] = 0; h1[i] = 0; }
    __syncthreads();
    for (i64 i = t; i < nv; i += 256) {
        float4 v = xv[i];
        u32 b;
        b = __float_as_uint(fabsf(v.x));
        if ((b >> 10) == q0) atomicAdd(&h0[b & 1023], 1u);
        if ((b >> 10) == q1) atomicAdd(&h1[b & 1023], 1u);
        b = __float_as_uint(fabsf(v.y));
        if ((b >> 10) == q0) atomicAdd(&h0[b & 1023], 1u);
        if ((b >> 10) == q1) atomicAdd(&h1[b & 1023], 1u);
        b = __float_as_uint(fabsf(v.z));
        if ((b >> 10) == q0) atomicAdd(&h0[b & 1023], 1u);
        if ((b >> 10) == q1) atomicAdd(&h1[b & 1023], 1u);
        b = __float_as_uint(fabsf(v.w));
        if ((b >> 10) == q0) atomicAdd(&h0[b & 1023], 1u);
        if ((b >> 10) == q1) atomicAdd(&h1[b & 1023], 1u);
    }
    if (t < rem) {
        u32 b = __float_as_uint(fabsf(xc[nv * 4 + t]));
        if ((b >> 10) == q0) atomicAdd(&h0[b & 1023], 1u);
        if ((b >> 10) == q1) atomicAdd(&h1[b & 1023], 1u);
    }
    __syncthreads();
    if (t < 4) pr[t] = 0;
    __syncthreads();
    block_select<4>(h0, st[1], ssum, &pr[0]);
    block_select<4>(h1, st[3], ssum, &pr[2]);
    if (t == 0) {
        u32 v0bits = (q0 << 10) | pr[0];
        u32 v1bits = (q1 << 10) | pr[2];
        mv[c] = np_lerp_f32(v0bits, v1bits, gamma);
    }
}

// ---------------- 256-bin index histogram (single-float4 coalesced) ----------------

__global__ __launch_bounds__(256) void k_hist_idx(const float* __restrict__ x, const float* __restrict__ mv,
                                                  u32* __restrict__ h256, i64 nper) {
    __shared__ u32 lh[8][257];
    const int c = blockIdx.y;
    const float m = mv[c];
    for (int i = threadIdx.x; i < 8 * 257; i += 256) (&lh[0][0])[i] = 0;
    __syncthreads();
    const float* xc = x + (i64)c * nper;
    const i64 nv = nper >> 2;
    const int copy = threadIdx.x & 7;
    const float4* xv = (const float4*)xc;
    for (i64 i = (i64)blockIdx.x * 256 + threadIdx.x; i < nv; i += (i64)gridDim.x * 256) {
        float4 v = xv[i];
        atomicAdd(&lh[copy][bin_index_f32(v.x, m)], 1u);
        atomicAdd(&lh[copy][bin_index_f32(v.y, m)], 1u);
        atomicAdd(&lh[copy][bin_index_f32(v.z, m)], 1u);
        atomicAdd(&lh[copy][bin_index_f32(v.w, m)], 1u);
    }
    if (blockIdx.x == 0 && threadIdx.x < (int)(nper & 3)) {
        atomicAdd(&lh[copy][bin_index_f32(xc[nv * 4 + threadIdx.x], m)], 1u);
    }
    __syncthreads();
    for (int i = threadIdx.x; i < BINS; i += 256) {
        u32 s = 0;
#pragma unroll
        for (int k = 0; k < 8; ++k) s += lh[k][i];
        if (s) atomicAdd(&h256[c * BINS + i], s);
    }
}

// ---------------- output: fused mask-table (f32 LDS) + out = x * mask[idx], nontemporal stores ----------------

__global__ __launch_bounds__(256) void k_output(const float* __restrict__ x, const float* __restrict__ mv,
                                                const float* __restrict__ hist_in, const float* __restrict__ logp_ref,
                                                const u32* __restrict__ h256, float* __restrict__ out, i64 nper) {
    __shared__ double smv_s[BINS];
    __shared__ float maskl[BINS];
    __shared__ double stot;
    const int c = blockIdx.y;
    const int b = threadIdx.x;
    // EMA with separately-rounded f32 ops, matching numpy ufunc-by-ufunc rounding
    float h = hist_in[c * BINS + b];
    float nn = (float)h256[c * BINS + b];
    float t = __fadd_rn(__fmul_rn(0.98f, h), __fmul_rn(0.02f, nn));
    float smf = __fadd_rn(t, 1e-8f);
    double sm = (double)smf;
    smv_s[b] = sm;
    __syncthreads();
    if (b < 64) {
        double s = smv_s[b] + smv_s[b + 64] + smv_s[b + 128] + smv_s[b + 192];
        for (int o = 32; o; o >>= 1) s += __shfl_down(s, o);
        if (b == 0) stot = s;
    }
    __syncthreads();
    double Lam = (double)logp_ref[c * BINS + b] - log(sm / stot);
    maskl[b] = (float)(1.0 / (1.0 + exp(Lam + 2.0)));   // sigmoid(-(Lam - THRESH)), THRESH = -2
    __syncthreads();

    const float m = mv[c];
    const float* xc = x + (i64)c * nper;
    float* oc = out + (i64)c * nper;
    const i64 nv = nper >> 2;
    const float4* xv = (const float4*)xc;
    float4n* ov = (float4n*)oc;
    for (i64 i = (i64)blockIdx.x * 256 + threadIdx.x; i < nv; i += (i64)gridDim.x * 256) {
        float4 v = xv[i];
        float4n o;
        o.x = (float)((double)v.x * (double)maskl[bin_index_f32(v.x, m)]);
        o.y = (float)((double)v.y * (double)maskl[bin_index_f32(v.y, m)]);
        o.z = (float)((double)v.z * (double)maskl[bin_index_f32(v.z, m)]);
        o.w = (float)((double)v.w * (double)maskl[bin_index_f32(v.w, m)]);
        __builtin_nontemporal_store(o, &ov[i]);   // keep x L3-resident during the write stream
    }
    if (blockIdx.x == 0 && threadIdx.x < (int)(nper & 3)) {
        i64 i = nv * 4 + threadIdx.x;
        float v = xc[i];
        oc[i] = (float)((double)v * (double)maskl[bin_index_f32(v, m)]);
    }
}

// ---------------- launch ----------------

extern "C" void kernel_launch(void* const* d_in, const int* in_sizes, int n_in,
                              void* d_out, int out_size, void* d_ws, size_t ws_size,
                              hipStream_t stream) {
    const float* x        = (const float*)d_in[0];
    const float* hist_in  = (const float*)d_in[1];
    const float* logp_ref = (const float*)d_in[2];
    float* out = (float*)d_out;

    const int C = in_sizes[1] / BINS;            // 5
    const i64 total = (i64)in_sizes[0];
    const i64 nper = total / C;                  // B*L = 8388608

    // ---- workspace: [zeroed control/hist region][fixed-slot candidate buffer] ----
    char* w = (char*)d_ws;
    size_t off = 0;
    float* mv   = (float*)(w + off); off += 4 * ((C + 7) & ~7);
    u32* h256   = (u32*)(w + off); off += 4 * BINS * C;
    u32* oflow  = (u32*)(w + off); off += 4 * C;
    u32* goob   = (u32*)(w + off); off += 4 * C;
    u32* flag   = (u32*)(w + off); off += 4 * C;
    u32* cselA  = (u32*)(w + off); off += 4 * 4 * C;
    u32* gha    = (u32*)(w + off); off += 4 * A_BINS * C;
    u32* g3a    = (u32*)(w + off); off += 4 * B_BINS * C;
    u32* g3b    = (u32*)(w + off); off += 4 * B_BINS * C;
    const size_t zbytes = off;
    off = (off + 255) & ~(size_t)255;
    u32* cand = (u32*)(w + off);
    const i64 ntot = (i64)NBLK * SLOT;                                // entries per channel
    const size_t cand_bytes = (size_t)4 * (size_t)C * (size_t)ntot;   // ~11.8 MB
    const int do_cand = (ws_size >= off + cand_bytes) ? 1 : 0;

    (void)hipMemsetAsync(d_ws, 0, zbytes, stream);

    const double virt = 0.99 * (double)(nper - 1);
    const i64 k0 = (i64)floor(virt);
    const double gamma = virt - (double)k0;
    const u32 needed = (u32)(nper - k0);   // top-count that must be in candidates

    dim3 blk(256);
    dim3 grd(NBLK, (unsigned)C);
    dim3 grd64(64, (unsigned)C);

    k_pass1<<<grd, blk, 0, stream>>>(x, cand, gha, oflow, goob, nper, do_cand);
    if (do_cand) {
        k_cselB_hist<<<grd64, blk, 0, stream>>>(cand, gha, oflow, goob, flag, cselA, g3a, g3b, ntot, needed);
    } else {
        k_flag_force<<<1, 64, 0, stream>>>(flag, C);
    }
    k_mv_final<<<(unsigned)C, blk, 0, stream>>>(x, flag, cselA, g3a, g3b, mv, nper, (u32)k0, gamma);
    k_hist_idx<<<grd, blk, 0, stream>>>(x, mv, h256, nper);
    k_output<<<grd, blk, 0, stream>>>(x, mv, hist_in, logp_ref, h256, out, nper);
}